// Round 10
// baseline (367.773 us; speedup 1.0000x reference)
//
#include <hip/hip_runtime.h>
#include <hip/hip_fp16.h>

#define N_NODES 100000
#define N_RELS  500
#define N_EDGES 1000000
#define SRCMASK 131071  // 2^17-1

// workspace layout (float offsets)
#define OFF_C     0         // 1
#define OFF_SUMS  64        // 64
#define OFF_SUMSQ 128       // 64
#define OFF_RSUM  320       // 64
#define OFF_RSQ   384       // 64
#define OFF_SR    576       // 500
#define OFF_RP    1088      // 32000 (r-branch pre-BN)
#define OFF_SX    33152     // 100000 (fp32)
#define OFF_DEG   133152    // 100000 ints; rewritten to cursor by scan3
#define OFF_OFF   233216    // 100001 ints (CSR offsets)
#define OFF_META  333248    // 1M uint2 = 2M uints
#define OFF_PRH   2333248   // 32000 halves
#define OFF_PXH   2349280   // 6.4M halves
#define OFF_ACCH  5549280   // 6.4M halves (pre-BN p rows, fp16)
#define OFF_PART  8749280   // 128 ints (scan partials)
// total ~8,749,408 floats = 33.4 MiB

typedef _Float16 h8 __attribute__((ext_vector_type(8)));
typedef float f4 __attribute__((ext_vector_type(4)));

// ---- fused rel-kernel: pr(fp16)+sr (from Wm right half), rp+stats (Wr), c --
__global__ void __launch_bounds__(256) k_rel(const float* __restrict__ r, const float* __restrict__ Wm,
                                             const float* __restrict__ Wr, const float* __restrict__ br,
                                             const float* __restrict__ aw, const float* __restrict__ bm,
                                             const float* __restrict__ que, float* __restrict__ ws) {
    __shared__ float wm[64][65];
    __shared__ float wr[64][65];
    __shared__ float awl[64];
    int tid = threadIdx.x;
    for (int i = tid; i < 4096; i += 256) {
        int row = i >> 6, col = i & 63;
        wm[row][col] = Wm[row * 128 + 64 + col];
        wr[row][col] = Wr[row * 64 + col];
    }
    if (tid < 64) awl[tid] = aw[tid];
    __syncthreads();
    int lane = tid & 63, wv = tid >> 6;
    int i = blockIdx.x * 4 + wv;  // grid 125 -> exactly 500
    float rv = r[i * 64 + lane];
    float p = 0.f, q = br[lane];
#pragma unroll
    for (int k = 0; k < 64; ++k) {
        float rk = __shfl(rv, k);
        p += wm[lane][k] * rk;
        q += wr[lane][k] * rk;
    }
    __half* prh = (__half*)(ws + OFF_PRH);
    prh[i * 64 + lane] = __float2half(p);
    ws[OFF_RP + i * 64 + lane] = q;
    atomicAdd(&ws[OFF_RSUM + lane], q);
    atomicAdd(&ws[OFF_RSQ + lane], q * q);
    float t = p * awl[lane];
    for (int o = 32; o > 0; o >>= 1) t += __shfl_down(t, o);
    if (lane == 0) ws[OFF_SR + i] = t;
    if (blockIdx.x == 0 && tid < 64) {
        float v = aw[tid] * bm[tid] + aw[64 + tid] * que[tid];
        for (int o = 32; o > 0; o >>= 1) v += __shfl_down(v, o);
        if (tid == 0) ws[OFF_C] = v;
    }
}

// ---- px via fp16 MFMA: px[n][c] = sum_k x[n][k] * Wm[c][k]; sx = px . aw ---
__global__ void __launch_bounds__(128) k_px(const float* __restrict__ x, const float* __restrict__ Wm,
                                            const float* __restrict__ aw, float* __restrict__ ws) {
    int tid = threadIdx.x;
    int lane = tid & 63, wv = tid >> 6;
    int wtile = blockIdx.x * 2 + wv;  // grid 3125 -> 6250 tiles of 16 nodes
    int n0 = wtile * 16;
    int rrow = lane & 15, grp = lane >> 4;  // grp 0..3

    h8 bfr[4][2];
    float awv[4];
#pragma unroll
    for (int ct = 0; ct < 4; ++ct) {
        int col = ct * 16 + rrow;
        awv[ct] = aw[col];
        const float* wp = Wm + col * 128;
#pragma unroll
        for (int h = 0; h < 2; ++h) {
            f4 w0 = *(const f4*)(wp + h * 32 + grp * 8);
            f4 w1 = *(const f4*)(wp + h * 32 + grp * 8 + 4);
            h8 b;
#pragma unroll
            for (int j = 0; j < 4; ++j) { b[j] = (_Float16)w0[j]; b[4 + j] = (_Float16)w1[j]; }
            bfr[ct][h] = b;
        }
    }
    const float* xp = x + (size_t)(n0 + rrow) * 64;
    h8 afr[2];
#pragma unroll
    for (int h = 0; h < 2; ++h) {
        f4 a0 = *(const f4*)(xp + h * 32 + grp * 8);
        f4 a1 = *(const f4*)(xp + h * 32 + grp * 8 + 4);
        h8 a;
#pragma unroll
        for (int j = 0; j < 4; ++j) { a[j] = (_Float16)a0[j]; a[4 + j] = (_Float16)a1[j]; }
        afr[h] = a;
    }
    f4 acc[4];
#pragma unroll
    for (int ct = 0; ct < 4; ++ct) acc[ct] = (f4){0.f, 0.f, 0.f, 0.f};
#pragma unroll
    for (int h = 0; h < 2; ++h)
#pragma unroll
        for (int ct = 0; ct < 4; ++ct)
            acc[ct] = __builtin_amdgcn_mfma_f32_16x16x32_f16(afr[h], bfr[ct][h], acc[ct], 0, 0, 0);

    __half* pxh = (__half*)(ws + OFF_PXH);
#pragma unroll
    for (int q = 0; q < 4; ++q) {
        int node = n0 + grp * 4 + q;
#pragma unroll
        for (int ct = 0; ct < 4; ++ct)
            pxh[(size_t)node * 64 + ct * 16 + rrow] = __float2half(acc[ct][q]);
        float t = acc[0][q] * awv[0] + acc[1][q] * awv[1] + acc[2][q] * awv[2] + acc[3][q] * awv[3];
        t += __shfl_xor(t, 1); t += __shfl_xor(t, 2); t += __shfl_xor(t, 4); t += __shfl_xor(t, 8);
        if (rrow == 0) ws[OFF_SX + node] = t;
    }
}

// ---- histogram of targets ---------------------------------------------------
__global__ void __launch_bounds__(256) k_hist(const int* __restrict__ ei, int* __restrict__ deg) {
    int e = blockIdx.x * 256 + threadIdx.x;
    if (e >= N_EDGES) return;
    atomicAdd(&deg[ei[N_EDGES + e]], 1);
}

// ---- scan phase 1: per-block (1000 nodes) local exclusive scan --------------
__global__ void __launch_bounds__(256) k_scan1(const int* __restrict__ deg, int* __restrict__ off,
                                               int* __restrict__ part) {
    __shared__ int ts[256];
    int tid = threadIdx.x;
    int idx0 = blockIdx.x * 1000 + tid * 4;
    int4 d = make_int4(0, 0, 0, 0);
    if (tid < 250) d = *(const int4*)(deg + idx0);
    int s = d.x + d.y + d.z + d.w;
    ts[tid] = s;
    __syncthreads();
    for (int o = 1; o < 256; o <<= 1) {
        int v = (tid >= o) ? ts[tid - o] : 0;
        __syncthreads();
        ts[tid] += v;
        __syncthreads();
    }
    int excl = ts[tid] - s;
    if (tid < 250) {
        off[idx0] = excl;
        off[idx0 + 1] = excl + d.x;
        off[idx0 + 2] = excl + d.x + d.y;
        off[idx0 + 3] = excl + d.x + d.y + d.z;
    }
    if (tid == 255) part[blockIdx.x] = ts[255];
}

// ---- scan phase 2: scan the 100 block totals --------------------------------
__global__ void __launch_bounds__(128) k_scan2(int* __restrict__ part, int* __restrict__ off) {
    __shared__ int ts[128];
    int tid = threadIdx.x;
    int v = (tid < 100) ? part[tid] : 0;
    ts[tid] = v;
    __syncthreads();
    for (int o = 1; o < 128; o <<= 1) {
        int u = (tid >= o) ? ts[tid - o] : 0;
        __syncthreads();
        ts[tid] += u;
        __syncthreads();
    }
    if (tid < 100) part[tid] = ts[tid] - v;  // exclusive base
    if (tid == 127) off[N_NODES] = ts[127];
}

// ---- scan phase 3: add base, write cursor -----------------------------------
__global__ void __launch_bounds__(256) k_scan3(int* __restrict__ off, const int* __restrict__ part,
                                               int* __restrict__ cursor) {
    int i = blockIdx.x * 256 + threadIdx.x;
    if (i >= N_NODES) return;
    int v = off[i] + part[i / 1000];
    off[i] = v;
    cursor[i] = v;
}

// ---- scatter: meta[pos] = (a_bits, src|at<<17) sorted by target -------------
__global__ void __launch_bounds__(256) k_scatter(const int* __restrict__ ei, const int* __restrict__ ea,
                                                 const float* __restrict__ ws, int* __restrict__ cursor,
                                                 uint2* __restrict__ meta) {
    int e = blockIdx.x * 256 + threadIdx.x;
    if (e >= N_EDGES) return;
    int src = ei[e], tgt = ei[N_EDGES + e], at = ea[e];
    float a = __expf(tanhf(ws[OFF_SX + src] + ws[OFF_SR + at] + ws[OFF_C]));
    int pos = atomicAdd(&cursor[tgt], 1);
    meta[pos] = make_uint2(__float_as_uint(a), (unsigned)src | ((unsigned)at << 17));
}

// ---- main: half2 edge-pairing — two edges per wave, dim-pair per lane -------
__global__ void __launch_bounds__(256) k_main(const int* __restrict__ off, const uint2* __restrict__ meta,
                                              const float* __restrict__ bm, float* __restrict__ ws) {
    __shared__ float bsum[64], bsq[64];
    int tid = threadIdx.x;
    int lane = tid & 63, wv = tid >> 6;
    if (tid < 64) { bsum[tid] = 0.f; bsq[tid] = 0.f; }
    __syncthreads();
    const __half* pxh = (const __half*)(ws + OFF_PXH);
    const __half* prh = (const __half*)(ws + OFF_PRH);
    __half* acch = (__half*)(ws + OFF_ACCH);
    int ld = lane & 31, hf = lane >> 5;  // dim-pair index, edge parity
    float2 bm2 = *(const float2*)(bm + 2 * ld);
    float ls0 = 0.f, ls1 = 0.f, lq0 = 0.f, lq1 = 0.f;
    int t0 = blockIdx.x * 32 + wv * 8;  // grid 3125 -> exactly 100000 targets
#pragma unroll 1
    for (int g = 0; g < 8; ++g) {
        int t = t0 + g;
        int s = off[t], e = off[t + 1];
        float ax = 0.f, ay = 0.f, asum = 0.f;
        int i = s;
        // 4 edge-pairs (8 edges) per iteration; this half handles parity hf
        for (; i + 8 <= e; i += 8) {
            uint2 m0 = meta[i + 0 + hf], m1 = meta[i + 2 + hf];
            uint2 m2 = meta[i + 4 + hf], m3 = meta[i + 6 + hf];
            float2 p0 = __half22float2(*(const __half2*)(pxh + (size_t)(m0.y & SRCMASK) * 64 + 2 * ld));
            float2 q0 = __half22float2(*(const __half2*)(prh + (m0.y >> 17) * 64 + 2 * ld));
            float2 p1 = __half22float2(*(const __half2*)(pxh + (size_t)(m1.y & SRCMASK) * 64 + 2 * ld));
            float2 q1 = __half22float2(*(const __half2*)(prh + (m1.y >> 17) * 64 + 2 * ld));
            float2 p2 = __half22float2(*(const __half2*)(pxh + (size_t)(m2.y & SRCMASK) * 64 + 2 * ld));
            float2 q2 = __half22float2(*(const __half2*)(prh + (m2.y >> 17) * 64 + 2 * ld));
            float2 p3 = __half22float2(*(const __half2*)(pxh + (size_t)(m3.y & SRCMASK) * 64 + 2 * ld));
            float2 q3 = __half22float2(*(const __half2*)(prh + (m3.y >> 17) * 64 + 2 * ld));
            float a0 = __uint_as_float(m0.x), a1 = __uint_as_float(m1.x);
            float a2 = __uint_as_float(m2.x), a3 = __uint_as_float(m3.x);
            ax += a0 * (p0.x + q0.x) + a1 * (p1.x + q1.x) + a2 * (p2.x + q2.x) + a3 * (p3.x + q3.x);
            ay += a0 * (p0.y + q0.y) + a1 * (p1.y + q1.y) + a2 * (p2.y + q2.y) + a3 * (p3.y + q3.y);
            asum += (a0 + a1) + (a2 + a3);
        }
        // pair tail (handles odd counts via clamp+select)
        for (; i < e; i += 2) {
            int j = i + hf;
            bool valid = j < e;
            uint2 m = meta[valid ? j : (e - 1)];
            float a = valid ? __uint_as_float(m.x) : 0.f;
            float2 p = __half22float2(*(const __half2*)(pxh + (size_t)(m.y & SRCMASK) * 64 + 2 * ld));
            float2 q = __half22float2(*(const __half2*)(prh + (m.y >> 17) * 64 + 2 * ld));
            ax += a * (p.x + q.x);
            ay += a * (p.y + q.y);
            asum += a;
        }
        // combine the two halves
        ax += __shfl_xor(ax, 32);
        ay += __shfl_xor(ay, 32);
        asum += __shfl_xor(asum, 32);
        float vx, vy;
        if (e > s) {
            float inv = 1.f / asum;
            vx = ax * inv + bm2.x;
            vy = ay * inv + bm2.y;
        } else { vx = 0.f; vy = 0.f; }
        if (hf == 0) {
            __half2 h2;
            h2.x = __float2half(vx);
            h2.y = __float2half(vy);
            *(__half2*)(acch + (size_t)t * 64 + 2 * ld) = h2;
        }
        ls0 += vx; lq0 += vx * vx;
        ls1 += vy; lq1 += vy * vy;
    }
    if (hf == 0) {
        atomicAdd(&bsum[2 * ld], ls0);
        atomicAdd(&bsq[2 * ld], lq0);
        atomicAdd(&bsum[2 * ld + 1], ls1);
        atomicAdd(&bsq[2 * ld + 1], lq1);
    }
    __syncthreads();
    if (tid < 64) {
        atomicAdd(&ws[OFF_SUMS + tid], bsum[tid]);
        atomicAdd(&ws[OFF_SUMSQ + tid], bsq[tid]);
    }
}

// ---- outputs: x-branch everywhere, r-branch fused into first 125 blocks -----
__global__ void __launch_bounds__(256) k_xout(const float* __restrict__ ws, const float* __restrict__ eg,
                                              const float* __restrict__ eb, const float* __restrict__ rg,
                                              const float* __restrict__ rb, float* __restrict__ out) {
    __shared__ float sc[64], sh[64], rsc[64], rsh[64];
    int tid = threadIdx.x;
    if (tid < 64) {
        float mean = ws[OFF_SUMS + tid] * (1.f / N_NODES);
        float var = ws[OFF_SUMSQ + tid] * (1.f / N_NODES) - mean * mean;
        float s = rsqrtf(var + 1e-5f) * eg[tid];
        sc[tid] = s;
        sh[tid] = eb[tid] - mean * s;
        float rmean = ws[OFF_RSUM + tid] * (1.f / N_RELS);
        float rvar = ws[OFF_RSQ + tid] * (1.f / N_RELS) - rmean * rmean;
        float rs = rsqrtf(rvar + 1e-5f) * rg[tid];
        rsc[tid] = rs;
        rsh[tid] = rb[tid] - rmean * rs;
    }
    __syncthreads();
    int lane = tid & 63, wv = tid >> 6;
    const __half* acch = (const __half*)(ws + OFF_ACCH);
    int base = blockIdx.x * 64;
    for (int it = 0; it < 16; ++it) {
        int t = base + it * 4 + wv;
        if (t < N_NODES) {
            float p = __half2float(acch[(size_t)t * 64 + lane]);
            out[(size_t)t * 64 + lane] = tanhf(p * sc[lane] + sh[lane]);
        }
    }
    if (blockIdx.x < 125) {
        int i = blockIdx.x * 4 + wv;  // 500 rels
        float p = ws[OFF_RP + i * 64 + lane];
        out[(size_t)N_NODES * 64 + (size_t)i * 64 + lane] = tanhf(p * rsc[lane] + rsh[lane]);
    }
}

extern "C" void kernel_launch(void* const* d_in, const int* in_sizes, int n_in,
                              void* d_out, int out_size, void* d_ws, size_t ws_size,
                              hipStream_t stream) {
    const float* x   = (const float*)d_in[0];
    const float* r   = (const float*)d_in[1];
    const float* que = (const float*)d_in[2];
    const int*   ei  = (const int*)d_in[3];
    const int*   ea  = (const int*)d_in[4];
    // d_in[5] edge_type unused by reference
    const float* Wm  = (const float*)d_in[6];
    const float* bm  = (const float*)d_in[7];
    const float* aw  = (const float*)d_in[8];
    const float* Wr  = (const float*)d_in[9];
    const float* br  = (const float*)d_in[10];
    const float* eg  = (const float*)d_in[11];
    const float* eb  = (const float*)d_in[12];
    const float* rg  = (const float*)d_in[13];
    const float* rb  = (const float*)d_in[14];
    float* out = (float*)d_out;
    float* ws  = (float*)d_ws;
    int*   deg  = (int*)(ws + OFF_DEG);
    int*   off  = (int*)(ws + OFF_OFF);
    int*   part = (int*)(ws + OFF_PART);
    uint2* meta = (uint2*)(ws + OFF_META);

    hipMemsetAsync(ws + OFF_SUMS, 0, 512 * sizeof(float), stream);  // all stat slots
    hipMemsetAsync(deg, 0, (size_t)N_NODES * sizeof(int), stream);

    k_rel<<<125, 256, 0, stream>>>(r, Wm, Wr, br, aw, bm, que, ws);
    k_px<<<3125, 128, 0, stream>>>(x, Wm, aw, ws);
    k_hist<<<(N_EDGES + 255) / 256, 256, 0, stream>>>(ei, deg);
    k_scan1<<<100, 256, 0, stream>>>(deg, off, part);
    k_scan2<<<1, 128, 0, stream>>>(part, off);
    k_scan3<<<(N_NODES + 255) / 256, 256, 0, stream>>>(off, part, deg);
    k_scatter<<<(N_EDGES + 255) / 256, 256, 0, stream>>>(ei, ea, ws, deg, meta);
    k_main<<<3125, 256, 0, stream>>>(off, meta, bm, ws);
    k_xout<<<(N_NODES + 63) / 64, 256, 0, stream>>>(ws, eg, eb, rg, rb, out);
}

// Round 11
// 319.498 us; speedup vs baseline: 1.1511x; 1.1511x over previous
//
#include <hip/hip_runtime.h>
#include <hip/hip_fp16.h>

#define N_NODES 100000
#define N_RELS  500
#define N_EDGES 1000000
#define SRCMASK 131071  // 2^17-1

// workspace layout (float offsets)
#define OFF_C     0         // 1
#define OFF_SUMS  64        // 64
#define OFF_SUMSQ 128       // 64
#define OFF_RSUM  320       // 64
#define OFF_RSQ   384       // 64
#define OFF_SR    576       // 500
#define OFF_RP    1088      // 32000 (r-branch pre-BN)
#define OFF_SX    33152     // 100000 (fp32)
#define OFF_DEG   133152    // 100000 ints; rewritten to cursor by scan3
#define OFF_OFF   233216    // 100001 ints (CSR offsets)
#define OFF_META  333248    // 1M uint2 = 2M uints
#define OFF_PRH   2333248   // 32000 halves
#define OFF_PXH   2349280   // 6.4M halves
#define OFF_ACCH  5549280   // 6.4M halves (pre-BN p rows, fp16)
#define OFF_PART  8749280   // 128 ints (scan partials)
// total ~8,749,408 floats = 33.4 MiB

typedef _Float16 h8 __attribute__((ext_vector_type(8)));
typedef float f4 __attribute__((ext_vector_type(4)));

__device__ __forceinline__ float4 h4tof4(uint2 u) {
    __half2 a = *(__half2*)&u.x, b = *(__half2*)&u.y;
    float2 fa = __half22float2(a), fb = __half22float2(b);
    return make_float4(fa.x, fa.y, fb.x, fb.y);
}

// ---- px via fp16 MFMA + init of deg and stat slots -------------------------
__global__ void __launch_bounds__(128) k_px(const float* __restrict__ x, const float* __restrict__ Wm,
                                            const float* __restrict__ aw, float* __restrict__ ws,
                                            int* __restrict__ deg) {
    int tid = threadIdx.x;
    // fold in zero-init (replaces two hipMemsetAsync dispatches)
    if (tid < 32) deg[blockIdx.x * 32 + tid] = 0;               // 3125*32 = 100000
    if (blockIdx.x == 0)
        for (int j = tid; j < 512; j += 128) ws[OFF_SUMS + j] = 0.f;
    int lane = tid & 63, wv = tid >> 6;
    int wtile = blockIdx.x * 2 + wv;  // grid 3125 -> 6250 tiles of 16 nodes
    int n0 = wtile * 16;
    int rrow = lane & 15, grp = lane >> 4;  // grp 0..3

    h8 bfr[4][2];
    float awv[4];
#pragma unroll
    for (int ct = 0; ct < 4; ++ct) {
        int col = ct * 16 + rrow;
        awv[ct] = aw[col];
        const float* wp = Wm + col * 128;
#pragma unroll
        for (int h = 0; h < 2; ++h) {
            f4 w0 = *(const f4*)(wp + h * 32 + grp * 8);
            f4 w1 = *(const f4*)(wp + h * 32 + grp * 8 + 4);
            h8 b;
#pragma unroll
            for (int j = 0; j < 4; ++j) { b[j] = (_Float16)w0[j]; b[4 + j] = (_Float16)w1[j]; }
            bfr[ct][h] = b;
        }
    }
    const float* xp = x + (size_t)(n0 + rrow) * 64;
    h8 afr[2];
#pragma unroll
    for (int h = 0; h < 2; ++h) {
        f4 a0 = *(const f4*)(xp + h * 32 + grp * 8);
        f4 a1 = *(const f4*)(xp + h * 32 + grp * 8 + 4);
        h8 a;
#pragma unroll
        for (int j = 0; j < 4; ++j) { a[j] = (_Float16)a0[j]; a[4 + j] = (_Float16)a1[j]; }
        afr[h] = a;
    }
    f4 acc[4];
#pragma unroll
    for (int ct = 0; ct < 4; ++ct) acc[ct] = (f4){0.f, 0.f, 0.f, 0.f};
#pragma unroll
    for (int h = 0; h < 2; ++h)
#pragma unroll
        for (int ct = 0; ct < 4; ++ct)
            acc[ct] = __builtin_amdgcn_mfma_f32_16x16x32_f16(afr[h], bfr[ct][h], acc[ct], 0, 0, 0);

    __half* pxh = (__half*)(ws + OFF_PXH);
#pragma unroll
    for (int q = 0; q < 4; ++q) {
        int node = n0 + grp * 4 + q;
#pragma unroll
        for (int ct = 0; ct < 4; ++ct)
            pxh[(size_t)node * 64 + ct * 16 + rrow] = __float2half(acc[ct][q]);
        float t = acc[0][q] * awv[0] + acc[1][q] * awv[1] + acc[2][q] * awv[2] + acc[3][q] * awv[3];
        t += __shfl_xor(t, 1); t += __shfl_xor(t, 2); t += __shfl_xor(t, 4); t += __shfl_xor(t, 8);
        if (rrow == 0) ws[OFF_SX + node] = t;
    }
}

// ---- fused rel-kernel: pr(fp16)+sr (from Wm right half), rp+stats (Wr), c --
__global__ void __launch_bounds__(256) k_rel(const float* __restrict__ r, const float* __restrict__ Wm,
                                             const float* __restrict__ Wr, const float* __restrict__ br,
                                             const float* __restrict__ aw, const float* __restrict__ bm,
                                             const float* __restrict__ que, float* __restrict__ ws) {
    __shared__ float wm[64][65];
    __shared__ float wr[64][65];
    __shared__ float awl[64];
    int tid = threadIdx.x;
    for (int i = tid; i < 4096; i += 256) {
        int row = i >> 6, col = i & 63;
        wm[row][col] = Wm[row * 128 + 64 + col];
        wr[row][col] = Wr[row * 64 + col];
    }
    if (tid < 64) awl[tid] = aw[tid];
    __syncthreads();
    int lane = tid & 63, wv = tid >> 6;
    int i = blockIdx.x * 4 + wv;  // grid 125 -> exactly 500
    float rv = r[i * 64 + lane];
    float p = 0.f, q = br[lane];
#pragma unroll
    for (int k = 0; k < 64; ++k) {
        float rk = __shfl(rv, k);
        p += wm[lane][k] * rk;
        q += wr[lane][k] * rk;
    }
    __half* prh = (__half*)(ws + OFF_PRH);
    prh[i * 64 + lane] = __float2half(p);
    ws[OFF_RP + i * 64 + lane] = q;
    atomicAdd(&ws[OFF_RSUM + lane], q);
    atomicAdd(&ws[OFF_RSQ + lane], q * q);
    float t = p * awl[lane];
    for (int o = 32; o > 0; o >>= 1) t += __shfl_down(t, o);
    if (lane == 0) ws[OFF_SR + i] = t;
    if (blockIdx.x == 0 && tid < 64) {
        float v = aw[tid] * bm[tid] + aw[64 + tid] * que[tid];
        for (int o = 32; o > 0; o >>= 1) v += __shfl_down(v, o);
        if (tid == 0) ws[OFF_C] = v;
    }
}

// ---- histogram of targets ---------------------------------------------------
__global__ void __launch_bounds__(256) k_hist(const int* __restrict__ ei, int* __restrict__ deg) {
    int e = blockIdx.x * 256 + threadIdx.x;
    if (e >= N_EDGES) return;
    atomicAdd(&deg[ei[N_EDGES + e]], 1);
}

// ---- scan phase 1: per-block (1000 nodes) local exclusive scan --------------
__global__ void __launch_bounds__(256) k_scan1(const int* __restrict__ deg, int* __restrict__ off,
                                               int* __restrict__ part) {
    __shared__ int ts[256];
    int tid = threadIdx.x;
    int idx0 = blockIdx.x * 1000 + tid * 4;
    int4 d = make_int4(0, 0, 0, 0);
    if (tid < 250) d = *(const int4*)(deg + idx0);
    int s = d.x + d.y + d.z + d.w;
    ts[tid] = s;
    __syncthreads();
    for (int o = 1; o < 256; o <<= 1) {
        int v = (tid >= o) ? ts[tid - o] : 0;
        __syncthreads();
        ts[tid] += v;
        __syncthreads();
    }
    int excl = ts[tid] - s;
    if (tid < 250) {
        off[idx0] = excl;
        off[idx0 + 1] = excl + d.x;
        off[idx0 + 2] = excl + d.x + d.y;
        off[idx0 + 3] = excl + d.x + d.y + d.z;
    }
    if (tid == 255) part[blockIdx.x] = ts[255];
}

// ---- scan phase 2+3 merged: every block locally scans 100 partials ----------
__global__ void __launch_bounds__(256) k_scan3(int* __restrict__ off, const int* __restrict__ part,
                                               int* __restrict__ cursor) {
    __shared__ int ts[128];
    int tid = threadIdx.x;
    if (tid < 128) ts[tid] = (tid < 100) ? part[tid] : 0;
    __syncthreads();
    for (int o = 1; o < 128; o <<= 1) {
        int v = 0;
        if (tid < 128 && tid >= o) v = ts[tid - o];
        __syncthreads();
        if (tid < 128) ts[tid] += v;
        __syncthreads();
    }
    int i = blockIdx.x * 256 + tid;
    if (i < N_NODES) {
        int bg = i / 1000;
        int base = (bg == 0) ? 0 : ts[bg - 1];
        int v = off[i] + base;
        off[i] = v;
        cursor[i] = v;
    }
    if (blockIdx.x == 0 && tid == 0) off[N_NODES] = ts[99];
}

// ---- scatter: meta[pos] = (a_bits, src|at<<17) sorted by target -------------
__global__ void __launch_bounds__(256) k_scatter(const int* __restrict__ ei, const int* __restrict__ ea,
                                                 const float* __restrict__ ws, int* __restrict__ cursor,
                                                 uint2* __restrict__ meta) {
    int e = blockIdx.x * 256 + threadIdx.x;
    if (e >= N_EDGES) return;
    int src = ei[e], tgt = ei[N_EDGES + e], at = ea[e];
    float a = __expf(tanhf(ws[OFF_SX + src] + ws[OFF_SR + at] + ws[OFF_C]));
    int pos = atomicAdd(&cursor[tgt], 1);
    meta[pos] = make_uint2(__float_as_uint(a), (unsigned)src | ((unsigned)at << 17));
}

// ---- main: quarter-wave per target, half4 gathers, no cross-lane epilogue ---
__global__ void __launch_bounds__(256) k_main(const int* __restrict__ off, const uint2* __restrict__ meta,
                                              const float* __restrict__ bm, float* __restrict__ ws) {
    __shared__ float bsum[64], bsq[64];
    int tid = threadIdx.x;
    if (tid < 64) { bsum[tid] = 0.f; bsq[tid] = 0.f; }
    __syncthreads();
    const __half* pxh = (const __half*)(ws + OFF_PXH);
    const __half* prh = (const __half*)(ws + OFF_PRH);
    __half* acch = (__half*)(ws + OFF_ACCH);
    int qlane = tid & 15;        // dim group: dims 4*qlane..+3
    int quarter = tid >> 4;      // 0..15 within block
    float4 bm4 = *(const float4*)(bm + 4 * qlane);
    float ls0 = 0.f, ls1 = 0.f, ls2 = 0.f, ls3 = 0.f;
    float lq0 = 0.f, lq1 = 0.f, lq2 = 0.f, lq3 = 0.f;
    int t0 = blockIdx.x * 64 + quarter * 4;  // 64 targets/block, 4 per quarter
#pragma unroll 1
    for (int g = 0; g < 4; ++g) {
        int t = t0 + g;
        bool tv = (t < N_NODES);
        int s = 0, e = 0;
        if (tv) { s = off[t]; e = off[t + 1]; }
        float ax = 0.f, ay = 0.f, az = 0.f, aw_ = 0.f, asum = 0.f;
        int i = s;
        for (; i + 2 <= e; i += 2) {
            uint2 m0 = meta[i], m1 = meta[i + 1];
            uint2 u0 = *(const uint2*)(pxh + (size_t)(m0.y & SRCMASK) * 64 + 4 * qlane);
            uint2 r0 = *(const uint2*)(prh + (m0.y >> 17) * 64 + 4 * qlane);
            uint2 u1 = *(const uint2*)(pxh + (size_t)(m1.y & SRCMASK) * 64 + 4 * qlane);
            uint2 r1 = *(const uint2*)(prh + (m1.y >> 17) * 64 + 4 * qlane);
            float a0 = __uint_as_float(m0.x), a1 = __uint_as_float(m1.x);
            float4 v0 = h4tof4(u0), w0 = h4tof4(r0);
            float4 v1 = h4tof4(u1), w1 = h4tof4(r1);
            ax += a0 * (v0.x + w0.x) + a1 * (v1.x + w1.x);
            ay += a0 * (v0.y + w0.y) + a1 * (v1.y + w1.y);
            az += a0 * (v0.z + w0.z) + a1 * (v1.z + w1.z);
            aw_ += a0 * (v0.w + w0.w) + a1 * (v1.w + w1.w);
            asum += a0 + a1;
        }
        if (i < e) {
            uint2 m0 = meta[i];
            uint2 u0 = *(const uint2*)(pxh + (size_t)(m0.y & SRCMASK) * 64 + 4 * qlane);
            uint2 r0 = *(const uint2*)(prh + (m0.y >> 17) * 64 + 4 * qlane);
            float a0 = __uint_as_float(m0.x);
            float4 v0 = h4tof4(u0), w0 = h4tof4(r0);
            ax += a0 * (v0.x + w0.x);
            ay += a0 * (v0.y + w0.y);
            az += a0 * (v0.z + w0.z);
            aw_ += a0 * (v0.w + w0.w);
            asum += a0;
        }
        float4 p;
        if (e > s) {
            float inv = 1.f / asum;
            p = make_float4(ax * inv + bm4.x, ay * inv + bm4.y, az * inv + bm4.z, aw_ * inv + bm4.w);
        } else {
            p = make_float4(0.f, 0.f, 0.f, 0.f);
        }
        if (tv) {
            __half2 h0 = __floats2half2_rn(p.x, p.y);
            __half2 h1 = __floats2half2_rn(p.z, p.w);
            uint2 st;
            st.x = *(unsigned*)&h0;
            st.y = *(unsigned*)&h1;
            *(uint2*)(acch + (size_t)t * 64 + 4 * qlane) = st;
        }
        ls0 += p.x; lq0 += p.x * p.x;
        ls1 += p.y; lq1 += p.y * p.y;
        ls2 += p.z; lq2 += p.z * p.z;
        ls3 += p.w; lq3 += p.w * p.w;
    }
    atomicAdd(&bsum[4 * qlane + 0], ls0);
    atomicAdd(&bsum[4 * qlane + 1], ls1);
    atomicAdd(&bsum[4 * qlane + 2], ls2);
    atomicAdd(&bsum[4 * qlane + 3], ls3);
    atomicAdd(&bsq[4 * qlane + 0], lq0);
    atomicAdd(&bsq[4 * qlane + 1], lq1);
    atomicAdd(&bsq[4 * qlane + 2], lq2);
    atomicAdd(&bsq[4 * qlane + 3], lq3);
    __syncthreads();
    if (tid < 64) {
        atomicAdd(&ws[OFF_SUMS + tid], bsum[tid]);
        atomicAdd(&ws[OFF_SUMSQ + tid], bsq[tid]);
    }
}

// ---- outputs: x-branch (half4 vectorized), r-branch in first 125 blocks -----
__global__ void __launch_bounds__(256) k_xout(const float* __restrict__ ws, const float* __restrict__ eg,
                                              const float* __restrict__ eb, const float* __restrict__ rg,
                                              const float* __restrict__ rb, float* __restrict__ out) {
    __shared__ float sc[64], sh[64], rsc[64], rsh[64];
    int tid = threadIdx.x;
    if (tid < 64) {
        float mean = ws[OFF_SUMS + tid] * (1.f / N_NODES);
        float var = ws[OFF_SUMSQ + tid] * (1.f / N_NODES) - mean * mean;
        float s = rsqrtf(var + 1e-5f) * eg[tid];
        sc[tid] = s;
        sh[tid] = eb[tid] - mean * s;
        float rmean = ws[OFF_RSUM + tid] * (1.f / N_RELS);
        float rvar = ws[OFF_RSQ + tid] * (1.f / N_RELS) - rmean * rmean;
        float rs = rsqrtf(rvar + 1e-5f) * rg[tid];
        rsc[tid] = rs;
        rsh[tid] = rb[tid] - rmean * rs;
    }
    __syncthreads();
    const __half* acch = (const __half*)(ws + OFF_ACCH);
    int qlane = tid & 15, quarter = tid >> 4;
    float s0 = sc[4 * qlane], s1 = sc[4 * qlane + 1], s2 = sc[4 * qlane + 2], s3 = sc[4 * qlane + 3];
    float h0 = sh[4 * qlane], h1 = sh[4 * qlane + 1], h2 = sh[4 * qlane + 2], h3 = sh[4 * qlane + 3];
    int n0 = blockIdx.x * 64 + quarter * 4;
#pragma unroll
    for (int g = 0; g < 4; ++g) {
        int n = n0 + g;
        if (n < N_NODES) {
            uint2 u = *(const uint2*)(acch + (size_t)n * 64 + 4 * qlane);
            float4 p = h4tof4(u);
            float4 o;
            o.x = tanhf(p.x * s0 + h0);
            o.y = tanhf(p.y * s1 + h1);
            o.z = tanhf(p.z * s2 + h2);
            o.w = tanhf(p.w * s3 + h3);
            *(float4*)(out + (size_t)n * 64 + 4 * qlane) = o;
        }
    }
    if (blockIdx.x < 125) {
        int lane = tid & 63, wv = tid >> 6;
        int i = blockIdx.x * 4 + wv;  // 500 rels
        float p = ws[OFF_RP + i * 64 + lane];
        out[(size_t)N_NODES * 64 + (size_t)i * 64 + lane] = tanhf(p * rsc[lane] + rsh[lane]);
    }
}

extern "C" void kernel_launch(void* const* d_in, const int* in_sizes, int n_in,
                              void* d_out, int out_size, void* d_ws, size_t ws_size,
                              hipStream_t stream) {
    const float* x   = (const float*)d_in[0];
    const float* r   = (const float*)d_in[1];
    const float* que = (const float*)d_in[2];
    const int*   ei  = (const int*)d_in[3];
    const int*   ea  = (const int*)d_in[4];
    // d_in[5] edge_type unused by reference
    const float* Wm  = (const float*)d_in[6];
    const float* bm  = (const float*)d_in[7];
    const float* aw  = (const float*)d_in[8];
    const float* Wr  = (const float*)d_in[9];
    const float* br  = (const float*)d_in[10];
    const float* eg  = (const float*)d_in[11];
    const float* eb  = (const float*)d_in[12];
    const float* rg  = (const float*)d_in[13];
    const float* rb  = (const float*)d_in[14];
    float* out = (float*)d_out;
    float* ws  = (float*)d_ws;
    int*   deg  = (int*)(ws + OFF_DEG);
    int*   off  = (int*)(ws + OFF_OFF);
    int*   part = (int*)(ws + OFF_PART);
    uint2* meta = (uint2*)(ws + OFF_META);

    k_px<<<3125, 128, 0, stream>>>(x, Wm, aw, ws, deg);
    k_rel<<<125, 256, 0, stream>>>(r, Wm, Wr, br, aw, bm, que, ws);
    k_hist<<<(N_EDGES + 255) / 256, 256, 0, stream>>>(ei, deg);
    k_scan1<<<100, 256, 0, stream>>>(deg, off, part);
    k_scan3<<<(N_NODES + 255) / 256, 256, 0, stream>>>(off, part, deg);
    k_scatter<<<(N_EDGES + 255) / 256, 256, 0, stream>>>(ei, ea, ws, deg, meta);
    k_main<<<(N_NODES + 63) / 64, 256, 0, stream>>>(off, meta, bm, ws);
    k_xout<<<(N_NODES + 63) / 64, 256, 0, stream>>>(ws, eg, eb, rg, rb, out);
}